// Round 12
// baseline (133.190 us; speedup 1.0000x reference)
//
#include <hip/hip_runtime.h>
#include <hip/hip_bf16.h>

// GCN 2-layer: x[N,128] @ W1[128,64] -> agg(+relu) -> @ W2[64,32] -> agg -> out[N,32]
// CSR-by-dst via bucket counting sort (R4/R5), fused fill (R10/R11). bf16
// intermediates (R6). Both GEMMs MFMA (R7/R11). Half/quarter-wave aggs (R10).
// R12: bucket_edges per-WAVE histogram (4x less LDS same-address atomic
// serialization); agg1 16-deep gather unroll (full mean-degree burst, 32 loads
// in flight per wave).

#define C_IN  128
#define C_HID 64
#define C_OUT 32
#define BK_SHIFT 10
#define BK_NODES (1 << BK_SHIFT)
#define BK_MAXB  128
#define EPB 2048   // edges per bucket_edges block

typedef unsigned short ushort_t;
typedef __attribute__((ext_vector_type(8))) short bf16x8;
typedef __attribute__((ext_vector_type(4))) float f32x4;

__device__ inline ushort_t f2bf(float f) {
    __hip_bfloat16 b = __float2bfloat16(f);   // RNE
    return *reinterpret_cast<ushort_t*>(&b);
}
__device__ inline float bflo(unsigned int v) { return __uint_as_float(v << 16); }
__device__ inline float bfhi(unsigned int v) { return __uint_as_float(v & 0xffff0000u); }

// ---------- CSR build ----------

__global__ void zero_bcur(int* __restrict__ bcur, int nb) {
    int i = threadIdx.x;
    if (i < nb) bcur[i] = 0;
}

// Phase A: partition edges into 1024-node dst buckets, bucket-major packed.
// Per-wave counters: contention on cnt is intra-wave only.
__global__ __launch_bounds__(256) void bucket_edges(
        const int* __restrict__ src, const int* __restrict__ dst,
        int* __restrict__ bcur, unsigned int* __restrict__ bucketed,
        int cap, int E, int nb) {
    __shared__ unsigned int stage[EPB];     // 8 KiB
    __shared__ unsigned char bkt[EPB];      // 2 KiB
    __shared__ int cnt[4][BK_MAXB];         // per-wave counts, 2 KiB
    __shared__ int wofs[4][BK_MAXB];        // per-wave base within bucket, 2 KiB
    __shared__ int lofs[BK_MAXB];
    __shared__ int base[BK_MAXB];
    __shared__ int tot[BK_MAXB];
    int tid = threadIdx.x, wid4 = tid >> 6;
    #pragma unroll
    for (int w = 0; w < 4; ++w)
        for (int i = tid; i < nb; i += 256) cnt[w][i] = 0;
    __syncthreads();
    int e0 = blockIdx.x * EPB;
    int myb[8]; int myr[8]; unsigned int mys[8];
    #pragma unroll
    for (int i = 0; i < 8; ++i) {
        int e = e0 + i * 256 + tid;
        if (e < E) {
            int d = dst[e];
            int s = src[e];
            int b = d >> BK_SHIFT;
            myb[i] = b;
            mys[i] = (unsigned int)s | ((unsigned int)(d & (BK_NODES - 1)) << 17);
            myr[i] = atomicAdd(&cnt[wid4][b], 1);
        } else myb[i] = -1;
    }
    __syncthreads();
    // per-bucket wave prefix + totals (one thread per bucket)
    if (tid < 128) {
        int b = tid;
        int c0 = cnt[0][b], c1 = cnt[1][b], c2 = cnt[2][b], c3 = cnt[3][b];
        tot[b] = c0 + c1 + c2 + c3;
        wofs[0][b] = 0;
        wofs[1][b] = c0;
        wofs[2][b] = c0 + c1;
        wofs[3][b] = c0 + c1 + c2;
    }
    __syncthreads();
    // exclusive scan of tot[0..nb) by first 2 waves
    if (tid < 128) {
        int lane = tid & 63, w = tid >> 6;
        int v = (tid < nb) ? tot[tid] : 0;
        int s = v;
        #pragma unroll
        for (int off = 1; off < 64; off <<= 1) {
            int t = __shfl_up(s, off, 64);
            if (lane >= off) s += t;
        }
        if (lane == 63) base[w] = s;   // reuse base[0..1] as wave sums briefly
        __syncthreads();
        int incl = s + ((w == 1) ? base[0] : 0);
        if (tid < nb) lofs[tid] = incl - v;
    } else {
        __syncthreads();
    }
    __syncthreads();
    // scatter into LDS stage, bucket-sorted
    #pragma unroll
    for (int i = 0; i < 8; ++i) {
        if (myb[i] >= 0) {
            int b = myb[i];
            int p = lofs[b] + wofs[wid4][b] + myr[i];
            stage[p] = mys[i];
            bkt[p] = (unsigned char)b;
        }
    }
    // reserve global space: one atomic per (block,bucket)
    for (int i = tid; i < nb; i += 256)
        base[i] = atomicAdd(&bcur[i], tot[i]);
    __syncthreads();
    // coalesced copy-out
    int total = min(EPB, E - e0);
    for (int p = tid; p < total; p += 256) {
        int b = bkt[p];
        int di = base[b] + (p - lofs[b]);
        if (di < cap)
            bucketed[(size_t)b * cap + di] = stage[p];
    }
}

// Fused per-bucket: inlined bucket prefix -> LDS degree histogram -> LDS scan
// -> offsets+dinv -> LDS-cursor csr fill.
__global__ __launch_bounds__(1024) void fill_csr_fused(
        const unsigned int* __restrict__ bucketed, const int* __restrict__ bcur,
        int* __restrict__ offsets, float* __restrict__ dinv,
        int* __restrict__ csr_src, int cap, int nb, int n) {
    __shared__ int hist[BK_NODES];
    __shared__ int wsum[16];
    __shared__ int sEb[BK_MAXB + 1];
    __shared__ int sW[2];
    int tid = threadIdx.x, lane = tid & 63, wid = tid >> 6;
    int b = blockIdx.x;
    int v128 = 0, s128 = 0;
    if (tid < 128) {
        v128 = (tid < nb) ? min(bcur[tid], cap) : 0;
        s128 = v128;
        #pragma unroll
        for (int off = 1; off < 64; off <<= 1) {
            int t = __shfl_up(s128, off, 64);
            if (lane >= off) s128 += t;
        }
        if (lane == 63) sW[wid] = s128;
    }
    __syncthreads();
    if (tid < 128) {
        int incl = s128 + ((wid == 1) ? sW[0] : 0);
        sEb[tid] = incl - v128;
        if (tid == nb - 1) sEb[nb] = incl;
    }
    hist[tid] = 0;
    __syncthreads();
    int eb = sEb[b];
    int cnt = sEb[b + 1] - eb;
    if (b == 0 && tid == 0) offsets[n] = sEb[nb];
    int node0 = b << BK_SHIFT;
    int nn = min(BK_NODES, n - node0);
    const unsigned int* bp = bucketed + (size_t)b * cap;
    for (int e = tid; e < cnt; e += 1024)
        atomicAdd(&hist[bp[e] >> 17], 1);
    __syncthreads();
    int v = hist[tid];
    int s = v;
    #pragma unroll
    for (int off = 1; off < 64; off <<= 1) {
        int t = __shfl_up(s, off, 64);
        if (lane >= off) s += t;
    }
    if (lane == 63) wsum[wid] = s;
    __syncthreads();
    if (wid == 0 && lane < 16) {
        int ws = wsum[lane];
        #pragma unroll
        for (int off = 1; off < 16; off <<= 1) {
            int t = __shfl_up(ws, off, 64);
            if (lane >= off) ws += t;
        }
        wsum[lane] = ws;
    }
    __syncthreads();
    int wpre = (wid > 0) ? wsum[wid - 1] : 0;
    int excl = wpre + s - v;
    if (tid < nn) {
        offsets[node0 + tid] = eb + excl;
        dinv[node0 + tid] = rsqrtf((float)v + 1.0f);
    }
    __syncthreads();
    hist[tid] = eb + excl;             // cursor
    __syncthreads();
    for (int e = tid; e < cnt; e += 1024) {
        unsigned int u = bp[e];
        int pos = atomicAdd(&hist[u >> 17], 1);
        csr_src[pos] = (int)(u & 0x1FFFFu);
    }
}

// ---- fallback path kernels (unused when workspace suffices) ----
__global__ void count_deg(const int* __restrict__ dst, int* __restrict__ deg, int E) {
    int idx = blockIdx.x * blockDim.x + threadIdx.x;
    int stride = gridDim.x * blockDim.x;
    for (int e = idx; e < E; e += stride)
        atomicAdd(&deg[dst[e]], 1);
}

__global__ void fill_csr(const int* __restrict__ src, const int* __restrict__ dst,
                         int* __restrict__ cursor, int* __restrict__ csr_src, int E) {
    int idx = blockIdx.x * blockDim.x + threadIdx.x;
    int stride = gridDim.x * blockDim.x;
    for (int e = idx; e < E; e += stride) {
        int pos = atomicAdd(&cursor[dst[e]], 1);
        csr_src[pos] = src[e];
    }
}

__global__ void scan_blocks(const int* __restrict__ deg, int* __restrict__ offsets,
                            int* __restrict__ bsums, float* __restrict__ dinv, int n) {
    __shared__ int wsum[16];
    int tid = threadIdx.x, lane = tid & 63, wid = tid >> 6;
    int i = blockIdx.x * 1024 + tid;
    int v = (i < n) ? deg[i] : 0;
    if (i < n) dinv[i] = rsqrtf((float)v + 1.0f);
    int s = v;
    #pragma unroll
    for (int off = 1; off < 64; off <<= 1) {
        int t = __shfl_up(s, off, 64);
        if (lane >= off) s += t;
    }
    if (lane == 63) wsum[wid] = s;
    __syncthreads();
    if (wid == 0 && lane < 16) {
        int ws = wsum[lane];
        #pragma unroll
        for (int off = 1; off < 16; off <<= 1) {
            int t = __shfl_up(ws, off, 64);
            if (lane >= off) ws += t;
        }
        wsum[lane] = ws;
        if (lane == 15) bsums[blockIdx.x] = ws;
    }
    __syncthreads();
    int wpre = (wid > 0) ? wsum[wid - 1] : 0;
    if (i < n) offsets[i] = wpre + s - v;
}

__global__ void scan_bsums(int* __restrict__ bsums, int nb) {
    __shared__ int wsum[16];
    int tid = threadIdx.x, lane = tid & 63, wid = tid >> 6;
    int v = (tid < nb) ? bsums[tid] : 0;
    int s = v;
    #pragma unroll
    for (int off = 1; off < 64; off <<= 1) {
        int t = __shfl_up(s, off, 64);
        if (lane >= off) s += t;
    }
    if (lane == 63) wsum[wid] = s;
    __syncthreads();
    if (wid == 0 && lane < 16) {
        int ws = wsum[lane];
        #pragma unroll
        for (int off = 1; off < 16; off <<= 1) {
            int t = __shfl_up(ws, off, 64);
            if (lane >= off) ws += t;
        }
        wsum[lane] = ws;
    }
    __syncthreads();
    int wpre = (wid > 0) ? wsum[wid - 1] : 0;
    if (tid < nb) bsums[tid] = wpre + s - v;
}

__global__ void scan_add(int* __restrict__ offsets, const int* __restrict__ bsums,
                         int n, int E) {
    int i = blockIdx.x * 1024 + threadIdx.x;
    if (i < n) offsets[i] += bsums[blockIdx.x];
    if (i == 0) offsets[n] = E;
}

// ---------- gemm1: x[N,128] @ W1[128,64] via MFMA bf16, f32 accum ----------
__global__ __launch_bounds__(256) void gemm1_mfma(
        const float* __restrict__ x, const float* __restrict__ W1,
        const float* __restrict__ dinv, ushort_t* __restrict__ xws_bf, int n) {
    __shared__ ushort_t Xs[64 * 136];      // padded row stride 136 (17408 B)
    __shared__ ushort_t Wl[16 * 64 * 8];   // [kblk][col][j] (16384 B)
    int tid = threadIdx.x;
    {
        const float4* Wv = reinterpret_cast<const float4*>(W1);  // 2048 float4
        #pragma unroll
        for (int p = 0; p < 8; ++p) {
            int idx = p * 256 + tid;
            float4 w = Wv[idx];
            int k = idx >> 4;            // 16 float4 per k-row (64 cols)
            int c0 = (idx & 15) * 4;
            ushort_t* d = &Wl[(k >> 3) * 512 + c0 * 8 + (k & 7)];
            d[0]  = f2bf(w.x);
            d[8]  = f2bf(w.y);
            d[16] = f2bf(w.z);
            d[24] = f2bf(w.w);
        }
    }
    int row0 = blockIdx.x * 64;
    {
        const float4* xv = reinterpret_cast<const float4*>(x + (size_t)row0 * C_IN);
        int maxv = min(64, n - row0) * (C_IN / 4);
        #pragma unroll
        for (int p = 0; p < 8; ++p) {
            int idx = p * 256 + tid;
            float4 v = (idx < maxv) ? xv[idx] : float4{0.f, 0.f, 0.f, 0.f};
            int row = idx >> 5, k4 = idx & 31;
            ushort4 pk;
            pk.x = f2bf(v.x); pk.y = f2bf(v.y); pk.z = f2bf(v.z); pk.w = f2bf(v.w);
            *reinterpret_cast<ushort4*>(&Xs[row * 136 + k4 * 4]) = pk;
        }
    }
    __syncthreads();
    int wid = tid >> 6, lane = tid & 63;
    int rbase = wid * 16;
    int l15 = lane & 15, kgrp = lane >> 4;
    f32x4 acc0 = {0.f, 0.f, 0.f, 0.f}, acc1 = acc0, acc2 = acc0, acc3 = acc0;
    #pragma unroll
    for (int kc = 0; kc < 4; ++kc) {
        bf16x8 a = *reinterpret_cast<const bf16x8*>(&Xs[(rbase + l15) * 136 + kc * 32 + kgrp * 8]);
        const ushort_t* wb = &Wl[(kc * 4 + kgrp) * 512 + l15 * 8];
        bf16x8 b0 = *reinterpret_cast<const bf16x8*>(wb);
        bf16x8 b1 = *reinterpret_cast<const bf16x8*>(wb + 128);
        bf16x8 b2 = *reinterpret_cast<const bf16x8*>(wb + 256);
        bf16x8 b3 = *reinterpret_cast<const bf16x8*>(wb + 384);
        acc0 = __builtin_amdgcn_mfma_f32_16x16x32_bf16(a, b0, acc0, 0, 0, 0);
        acc1 = __builtin_amdgcn_mfma_f32_16x16x32_bf16(a, b1, acc1, 0, 0, 0);
        acc2 = __builtin_amdgcn_mfma_f32_16x16x32_bf16(a, b2, acc2, 0, 0, 0);
        acc3 = __builtin_amdgcn_mfma_f32_16x16x32_bf16(a, b3, acc3, 0, 0, 0);
    }
    #pragma unroll
    for (int j = 0; j < 4; ++j) {
        int row = row0 + rbase + kgrp * 4 + j;
        if (row < n) {
            float di = dinv[row];
            ushort_t* o = &xws_bf[(size_t)row * C_HID + l15];
            o[0]  = f2bf(di * acc0[j]);
            o[16] = f2bf(di * acc1[j]);
            o[32] = f2bf(di * acc2[j]);
            o[48] = f2bf(di * acc3[j]);
        }
    }
}

// ---------- gemm2: h[N,64] @ W2[64,32] via MFMA bf16 (h already bf16) ----------
__global__ __launch_bounds__(256) void gemm2_mfma(
        const ushort_t* __restrict__ h_bf, const float* __restrict__ W2,
        const float* __restrict__ dinv, ushort_t* __restrict__ xws2_bf, int n) {
    __shared__ ushort_t Hs[64 * 72];       // padded stride 72 (9216 B)
    __shared__ ushort_t Wl[8 * 32 * 8];    // [kblk][col][j] (4096 B)
    int tid = threadIdx.x;
    {
        const float4* Wv = reinterpret_cast<const float4*>(W2);  // 512 float4
        #pragma unroll
        for (int p = 0; p < 2; ++p) {
            int idx = p * 256 + tid;
            float4 w = Wv[idx];
            int k = idx >> 3;            // 8 float4 per k-row (32 cols)
            int c0 = (idx & 7) * 4;
            ushort_t* d = &Wl[(k >> 3) * 256 + c0 * 8 + (k & 7)];
            d[0]  = f2bf(w.x);
            d[8]  = f2bf(w.y);
            d[16] = f2bf(w.z);
            d[24] = f2bf(w.w);
        }
    }
    int row0 = blockIdx.x * 64;
    {
        const uint4* hv = reinterpret_cast<const uint4*>(h_bf + (size_t)row0 * C_HID);
        int maxv = min(64, n - row0) * 8;  // uint4 per row
        #pragma unroll
        for (int p = 0; p < 2; ++p) {
            int idx = p * 256 + tid;
            uint4 v = (idx < maxv) ? hv[idx] : uint4{0u, 0u, 0u, 0u};
            int row = idx >> 3, c16 = idx & 7;
            *reinterpret_cast<uint4*>(&Hs[row * 72 + c16 * 8]) = v;
        }
    }
    __syncthreads();
    int wid = tid >> 6, lane = tid & 63;
    int rbase = wid * 16;
    int l15 = lane & 15, kgrp = lane >> 4;
    f32x4 acc0 = {0.f, 0.f, 0.f, 0.f}, acc1 = acc0;
    #pragma unroll
    for (int kc = 0; kc < 2; ++kc) {
        bf16x8 a = *reinterpret_cast<const bf16x8*>(&Hs[(rbase + l15) * 72 + kc * 32 + kgrp * 8]);
        const ushort_t* wb = &Wl[(kc * 4 + kgrp) * 256 + l15 * 8];
        bf16x8 b0 = *reinterpret_cast<const bf16x8*>(wb);
        bf16x8 b1 = *reinterpret_cast<const bf16x8*>(wb + 128);
        acc0 = __builtin_amdgcn_mfma_f32_16x16x32_bf16(a, b0, acc0, 0, 0, 0);
        acc1 = __builtin_amdgcn_mfma_f32_16x16x32_bf16(a, b1, acc1, 0, 0, 0);
    }
    #pragma unroll
    for (int j = 0; j < 4; ++j) {
        int row = row0 + rbase + kgrp * 4 + j;
        if (row < n) {
            float di = dinv[row];
            ushort_t* o = &xws2_bf[(size_t)row * C_OUT + l15];
            o[0]  = f2bf(di * acc0[j]);
            o[16] = f2bf(di * acc1[j]);
        }
    }
}

// ---------- Aggregations: one node per half/quarter wave, no shuffles ----------

// agg1: half-wave (32 lanes x uint = 64 ch) owns one node; 16-deep gather burst
// covers the mean degree in one shot (32 loads in flight per wave).
__global__ void agg1(const ushort_t* __restrict__ xws_bf, const float* __restrict__ dinv,
                     const int* __restrict__ offsets, const int* __restrict__ csr_src,
                     const float* __restrict__ b1, ushort_t* __restrict__ h_bf, int n) {
    int wid = threadIdx.x >> 6, lane = threadIdx.x & 63;
    int half = lane >> 5, c2 = lane & 31;
    const unsigned int* xu = reinterpret_cast<const unsigned int*>(xws_bf);
    float2 bb = *reinterpret_cast<const float2*>(&b1[2 * c2]);
    for (int base = (blockIdx.x * 4 + wid) * 2; base < n; base += gridDim.x * 8) {
        int i = base + half;
        if (i < n) {
            int beg = offsets[i], end = offsets[i + 1];
            float di = dinv[i];
            unsigned int sv = xu[(size_t)i * 32 + c2];     // self-loop term
            float a0 = bflo(sv), a1 = bfhi(sv);
            int k = beg;
            for (; k + 16 <= end; k += 16) {
                int si[16];
                unsigned int vv[16];
                #pragma unroll
                for (int t = 0; t < 16; ++t) si[t] = csr_src[k + t];
                #pragma unroll
                for (int t = 0; t < 16; ++t) vv[t] = xu[(size_t)si[t] * 32 + c2];
                float l0 = 0.f, h0 = 0.f;
                #pragma unroll
                for (int t = 0; t < 16; ++t) { l0 += bflo(vv[t]); h0 += bfhi(vv[t]); }
                a0 += l0; a1 += h0;
            }
            for (; k + 8 <= end; k += 8) {
                int si[8];
                unsigned int vv[8];
                #pragma unroll
                for (int t = 0; t < 8; ++t) si[t] = csr_src[k + t];
                #pragma unroll
                for (int t = 0; t < 8; ++t) vv[t] = xu[(size_t)si[t] * 32 + c2];
                #pragma unroll
                for (int t = 0; t < 8; ++t) { a0 += bflo(vv[t]); a1 += bfhi(vv[t]); }
            }
            for (; k + 4 <= end; k += 4) {
                int s0 = csr_src[k + 0];
                int s1 = csr_src[k + 1];
                int s2 = csr_src[k + 2];
                int s3 = csr_src[k + 3];
                unsigned int v0 = xu[(size_t)s0 * 32 + c2];
                unsigned int v1 = xu[(size_t)s1 * 32 + c2];
                unsigned int v2 = xu[(size_t)s2 * 32 + c2];
                unsigned int v3 = xu[(size_t)s3 * 32 + c2];
                a0 += (bflo(v0) + bflo(v1)) + (bflo(v2) + bflo(v3));
                a1 += (bfhi(v0) + bfhi(v1)) + (bfhi(v2) + bfhi(v3));
            }
            for (; k < end; ++k) {
                int s = csr_src[k];
                unsigned int v = xu[(size_t)s * 32 + c2];
                a0 += bflo(v); a1 += bfhi(v);
            }
            float r0 = fmaxf(di * a0 + bb.x, 0.f);
            float r1 = fmaxf(di * a1 + bb.y, 0.f);
            unsigned int pk = (unsigned int)f2bf(r0) | ((unsigned int)f2bf(r1) << 16);
            *reinterpret_cast<unsigned int*>(&h_bf[(size_t)i * C_HID + 2 * c2]) = pk;
        }
    }
}

// agg2: quarter-wave (16 lanes x uint = 32 ch) owns one node; 8-deep unroll.
__global__ void agg2(const ushort_t* __restrict__ xws2_bf, const float* __restrict__ dinv,
                     const int* __restrict__ offsets, const int* __restrict__ csr_src,
                     const float* __restrict__ b2, float* __restrict__ out, int n) {
    int wid = threadIdx.x >> 6, lane = threadIdx.x & 63;
    int q = lane >> 4, c2 = lane & 15;
    const unsigned int* xu = reinterpret_cast<const unsigned int*>(xws2_bf);
    float2 bb = *reinterpret_cast<const float2*>(&b2[2 * c2]);
    for (int base = (blockIdx.x * 4 + wid) * 4; base < n; base += gridDim.x * 16) {
        int i = base + q;
        if (i < n) {
            int beg = offsets[i], end = offsets[i + 1];
            float di = dinv[i];
            unsigned int sv = xu[(size_t)i * 16 + c2];
            float a0 = bflo(sv), a1 = bfhi(sv);
            int k = beg;
            for (; k + 8 <= end; k += 8) {
                int si[8];
                unsigned int vv[8];
                #pragma unroll
                for (int t = 0; t < 8; ++t) si[t] = csr_src[k + t];
                #pragma unroll
                for (int t = 0; t < 8; ++t) vv[t] = xu[(size_t)si[t] * 16 + c2];
                #pragma unroll
                for (int t = 0; t < 8; ++t) { a0 += bflo(vv[t]); a1 += bfhi(vv[t]); }
            }
            for (; k + 4 <= end; k += 4) {
                int s0 = csr_src[k + 0];
                int s1 = csr_src[k + 1];
                int s2 = csr_src[k + 2];
                int s3 = csr_src[k + 3];
                unsigned int v0 = xu[(size_t)s0 * 16 + c2];
                unsigned int v1 = xu[(size_t)s1 * 16 + c2];
                unsigned int v2 = xu[(size_t)s2 * 16 + c2];
                unsigned int v3 = xu[(size_t)s3 * 16 + c2];
                a0 += (bflo(v0) + bflo(v1)) + (bflo(v2) + bflo(v3));
                a1 += (bfhi(v0) + bfhi(v1)) + (bfhi(v2) + bfhi(v3));
            }
            for (; k < end; ++k) {
                int s = csr_src[k];
                unsigned int v = xu[(size_t)s * 16 + c2];
                a0 += bflo(v); a1 += bfhi(v);
            }
            float2 r;
            r.x = di * a0 + bb.x;
            r.y = di * a1 + bb.y;
            *reinterpret_cast<float2*>(&out[(size_t)i * C_OUT + 2 * c2]) = r;
        }
    }
}

extern "C" void kernel_launch(void* const* d_in, const int* in_sizes, int n_in,
                              void* d_out, int out_size, void* d_ws, size_t ws_size,
                              hipStream_t stream) {
    const float* x  = (const float*)d_in[0];
    const int*   ei = (const int*)d_in[1];
    const float* W1 = (const float*)d_in[2];
    const float* b1 = (const float*)d_in[3];
    const float* W2 = (const float*)d_in[4];
    const float* b2 = (const float*)d_in[5];
    float* out = (float*)d_out;

    const int N = in_sizes[0] / C_IN;      // 100000
    const int E = in_sizes[1] / 2;         // 1600000
    const int* src = ei;
    const int* dst = ei + E;

    const int NB = (N + BK_NODES - 1) >> BK_SHIFT;          // 98
    const int CAP = (2 * (E / NB) + 1023) & ~1023;          // 32768 (2x mean)

    char* ws = (char*)d_ws;
    size_t off = 0;
    auto alloc = [&](size_t bytes) { char* p = ws + off; off += (bytes + 255) & ~(size_t)255; return p; };
    ushort_t* xw_bf  = (ushort_t*)alloc((size_t)N * C_HID * 2);  // xws1, reused as xws2
    ushort_t* h_bf   = (ushort_t*)alloc((size_t)N * C_HID * 2);
    int*   deg     = (int*)alloc((size_t)N * 4);       // fallback only
    float* dinv    = (float*)alloc((size_t)N * 4);
    int*   offsets = (int*)alloc((size_t)(N + 1) * 4);
    int*   cursor  = (int*)alloc((size_t)N * 4);       // fallback only
    int*   csr_src = (int*)alloc((size_t)E * 4);
    int*   bsums   = (int*)alloc(4096);                // fallback only
    int*   bcur    = (int*)alloc((size_t)BK_MAXB * 4);
    unsigned int* bucketed = (unsigned int*)alloc((size_t)NB * CAP * 4);
    bool use_bucket = (off <= ws_size) && (NB <= BK_MAXB) && (N < (1 << 17));

    const int nb1024 = (N + 1023) / 1024;  // 98

    if (use_bucket) {
        zero_bcur<<<1, 128, 0, stream>>>(bcur, NB);
        bucket_edges<<<(E + EPB - 1) / EPB, 256, 0, stream>>>(
            src, dst, bcur, bucketed, CAP, E, NB);
        fill_csr_fused<<<NB, 1024, 0, stream>>>(bucketed, bcur, offsets, dinv,
                                                csr_src, CAP, NB, N);
    } else {
        hipMemsetAsync(deg, 0, (size_t)N * 4, stream);
        count_deg<<<2048, 256, 0, stream>>>(dst, deg, E);
        scan_blocks<<<nb1024, 1024, 0, stream>>>(deg, offsets, bsums, dinv, N);
        scan_bsums<<<1, 1024, 0, stream>>>(bsums, nb1024);
        scan_add<<<nb1024, 1024, 0, stream>>>(offsets, bsums, N, E);
        hipMemcpyAsync(cursor, offsets, (size_t)N * 4, hipMemcpyDeviceToDevice, stream);
        fill_csr<<<2048, 256, 0, stream>>>(src, dst, cursor, csr_src, E);
    }

    gemm1_mfma<<<(N + 63) / 64, 256, 0, stream>>>(x, W1, dinv, xw_bf, N);
    agg1<<<2048, 256, 0, stream>>>(xw_bf, dinv, offsets, csr_src, b1, h_bf, N);
    gemm2_mfma<<<(N + 63) / 64, 256, 0, stream>>>(h_bf, W2, dinv, xw_bf, N);
    agg2<<<2048, 256, 0, stream>>>(xw_bf, dinv, offsets, csr_src, b2, out, N);
}